// Round 1
// baseline (140.965 us; speedup 1.0000x reference)
//
#include <hip/hip_runtime.h>

#define M_ROWS 1024
#define DIM 512
#define N_TOT 7168           // M + 2*M*C
#define TEXT_OFF 1024        // M
#define SHUF_OFF 4096        // M + M*C
#define INV_T (1.0f/0.07f)
#define MARGIN_V 0.2f

#define BM 128
#define BN 128
#define BK 32
#define LDSS 40              // padded LDS stride (bf16 elems): 80B -> 2-way bank alias (free)

typedef __attribute__((ext_vector_type(8))) short bf16x8;
typedef __attribute__((ext_vector_type(4))) float f32x4;

__device__ __forceinline__ ushort f2bf(float f) {
  unsigned u = __float_as_uint(f);
  u += 0x7fffu + ((u >> 16) & 1u);   // RTNE
  return (ushort)(u >> 16);
}

// ---------------- Kernel 1: normalize + cast bf16 + build ids ----------------
__global__ __launch_bounds__(256) void k_normalize(
    const float* __restrict__ motion, const float* __restrict__ text,
    const float* __restrict__ shuf, const int* __restrict__ mids,
    ushort* __restrict__ emb, int* __restrict__ ids) {
  int wave = threadIdx.x >> 6;
  int lane = threadIdx.x & 63;
  int row = blockIdx.x * 4 + wave;
  if (row >= N_TOT) return;
  const float* src;
  int id;
  if (row < TEXT_OFF) { src = motion + (size_t)row * DIM; id = mids[row]; }
  else if (row < SHUF_OFF) { int r = row - TEXT_OFF; src = text + (size_t)r * DIM; id = mids[r / 3]; }
  else { int r = row - SHUF_OFF; src = shuf + (size_t)r * DIM; id = mids[r / 3] + 100000; }

  float4 a = ((const float4*)src)[lane * 2];
  float4 b = ((const float4*)src)[lane * 2 + 1];
  float v0 = a.x + 1e-8f, v1 = a.y + 1e-8f, v2 = a.z + 1e-8f, v3 = a.w + 1e-8f;
  float v4 = b.x + 1e-8f, v5 = b.y + 1e-8f, v6 = b.z + 1e-8f, v7 = b.w + 1e-8f;
  float ss = v0*v0 + v1*v1 + v2*v2 + v3*v3 + v4*v4 + v5*v5 + v6*v6 + v7*v7;
  #pragma unroll
  for (int m = 1; m < 64; m <<= 1) ss += __shfl_xor(ss, m);
  float inv = 1.0f / fmaxf(sqrtf(ss), 1e-12f);

  uint w0 = (uint)f2bf(v0 * inv) | ((uint)f2bf(v1 * inv) << 16);
  uint w1 = (uint)f2bf(v2 * inv) | ((uint)f2bf(v3 * inv) << 16);
  uint w2 = (uint)f2bf(v4 * inv) | ((uint)f2bf(v5 * inv) << 16);
  uint w3 = (uint)f2bf(v6 * inv) | ((uint)f2bf(v7 * inv) << 16);
  uint4 pk; pk.x = w0; pk.y = w1; pk.z = w2; pk.w = w3;
  *((uint4*)(emb + (size_t)row * DIM + lane * 8)) = pk;
  if (lane == 0) ids[row] = id;
}

// ---------------- Kernel 2: fused A*A^T + masked row reductions ----------------
__global__ __launch_bounds__(256) void k_gemm_loss(
    const ushort* __restrict__ emb, const int* __restrict__ ids,
    float* __restrict__ denom, float* __restrict__ possum, float* __restrict__ margsum) {
  __shared__ short As[BM][LDSS];
  __shared__ short Bs[BN][LDSS];
  __shared__ int rid[BM];
  __shared__ int cid[BN];

  int t = threadIdx.x;
  int lane = t & 63;
  int wave = t >> 6;
  int brow = blockIdx.x * BM;
  int bcol = blockIdx.y * BN;
  int wrow = (wave >> 1) * 64;
  int wcol = (wave & 1) * 64;

  if (t < BM) rid[t] = ids[brow + t];
  else cid[t - BM] = ids[bcol + (t - BM)];

  f32x4 acc[4][4];
  #pragma unroll
  for (int m = 0; m < 4; m++)
    #pragma unroll
    for (int n = 0; n < 4; n++)
      acc[m][n] = (f32x4){0.f, 0.f, 0.f, 0.f};

  int srow = t >> 2;          // 0..63
  int scol = (t & 3) * 8;     // bf16 element offset within K-chunk

  for (int kk = 0; kk < DIM; kk += BK) {
    __syncthreads();
    #pragma unroll
    for (int it = 0; it < 2; it++) {
      int r = srow + it * 64;
      uint4 va = *(const uint4*)(emb + (size_t)(brow + r) * DIM + kk + scol);
      uint4 vb = *(const uint4*)(emb + (size_t)(bcol + r) * DIM + kk + scol);
      *(uint4*)(&As[r][scol]) = va;
      *(uint4*)(&Bs[r][scol]) = vb;
    }
    __syncthreads();

    bf16x8 aF[4], bF[4];
    #pragma unroll
    for (int m = 0; m < 4; m++)
      aF[m] = *(const bf16x8*)(&As[wrow + m * 16 + (lane & 15)][(lane >> 4) * 8]);
    #pragma unroll
    for (int n = 0; n < 4; n++)
      bF[n] = *(const bf16x8*)(&Bs[wcol + n * 16 + (lane & 15)][(lane >> 4) * 8]);
    #pragma unroll
    for (int m = 0; m < 4; m++)
      #pragma unroll
      for (int n = 0; n < 4; n++)
        acc[m][n] = __builtin_amdgcn_mfma_f32_16x16x32_bf16(aF[m], bF[n], acc[m][n], 0, 0, 0);
  }

  // Post-process: per element masks + per-row partial reductions.
  int cgrp = lane >> 4;   // 0..3
  int cl = lane & 15;
  #pragma unroll
  for (int m = 0; m < 4; m++) {
    #pragma unroll
    for (int r = 0; r < 4; r++) {
      int row_l = wrow + m * 16 + cgrp * 4 + r;
      int i = brow + row_l;
      int idi = rid[row_l];
      float dsum = 0.f, psum = 0.f, msum = 0.f;
      #pragma unroll
      for (int n = 0; n < 4; n++) {
        int col_l = wcol + n * 16 + cl;
        int j = bcol + col_l;
        float sim = acc[m][n][r] * INV_T;
        if (i != j) {
          float e = __expf(sim);
          dsum += e;
          if (idi == cid[col_l]) psum += sim;
          else msum += fmaxf(sim + MARGIN_V, 0.f);
        }
      }
      #pragma unroll
      for (int s = 1; s < 16; s <<= 1) {
        dsum += __shfl_xor(dsum, s);
        psum += __shfl_xor(psum, s);
        msum += __shfl_xor(msum, s);
      }
      if (cl == 0) {
        atomicAdd(&denom[i], dsum);
        atomicAdd(&possum[i], psum);
        atomicAdd(&margsum[i], msum);
      }
    }
  }
}

// ---------------- Kernel 3: finalize ----------------
__global__ __launch_bounds__(256) void k_finalize(
    const int* __restrict__ mids, const float* __restrict__ denom,
    const float* __restrict__ possum, const float* __restrict__ margsum,
    float* __restrict__ out) {
  __shared__ int hist[256];
  __shared__ double red[256];
  __shared__ int redc[256];
  int t = threadIdx.x;
  hist[t] = 0;
  __syncthreads();
  for (int i = t; i < M_ROWS; i += 256) atomicAdd(&hist[mids[i]], 1);
  __syncthreads();

  double tot = 0.0;
  int cnt = 0;
  for (int i = t; i < N_TOT; i += 256) {
    int v; bool shuf = false;
    if (i < TEXT_OFF) v = mids[i];
    else if (i < SHUF_OFF) v = mids[(i - TEXT_OFF) / 3];
    else { v = mids[(i - SHUF_OFF) / 3]; shuf = true; }
    int c = hist[v];
    int npos = shuf ? (3 * c - 1) : (4 * c - 1);
    int nneg = N_TOT - 1 - npos;
    if (npos > 0 && nneg > 0) {
      float infonce = logf(denom[i]) - possum[i] / (float)(npos > 1 ? npos : 1);
      float marg = margsum[i] / (float)(nneg > 1 ? nneg : 1);
      tot += (double)(infonce + marg);
      cnt++;
    }
  }
  red[t] = tot; redc[t] = cnt;
  __syncthreads();
  for (int s = 128; s > 0; s >>= 1) {
    if (t < s) { red[t] += red[t + s]; redc[t] += redc[t + s]; }
    __syncthreads();
  }
  if (t == 0) {
    out[0] = (redc[0] > 0) ? (float)(red[0] / (double)redc[0]) : 0.f;
  }
}

// ---------------- Launch ----------------
extern "C" void kernel_launch(void* const* d_in, const int* in_sizes, int n_in,
                              void* d_out, int out_size, void* d_ws, size_t ws_size,
                              hipStream_t stream) {
  const float* motion = (const float*)d_in[0];
  const float* text   = (const float*)d_in[1];
  const float* shuf   = (const float*)d_in[2];
  const int*   mids   = (const int*)d_in[3];

  char* ws = (char*)d_ws;
  ushort* emb = (ushort*)ws;                                  // N*D bf16 = 7,340,032 B
  int* ids    = (int*)(ws + (size_t)N_TOT * DIM * 2);         // N*4
  float* denom = (float*)(ws + (size_t)N_TOT * DIM * 2 + (size_t)N_TOT * 4);
  float* possum  = denom + N_TOT;
  float* margsum = denom + 2 * N_TOT;

  hipMemsetAsync(denom, 0, 3 * (size_t)N_TOT * sizeof(float), stream);

  k_normalize<<<N_TOT / 4, 256, 0, stream>>>(motion, text, shuf, mids, emb, ids);
  k_gemm_loss<<<dim3(N_TOT / BM, N_TOT / BN), 256, 0, stream>>>(emb, ids, denom, possum, margsum);
  k_finalize<<<1, 256, 0, stream>>>(mids, denom, possum, margsum, (float*)d_out);
}

// Round 2
// 118.791 us; speedup vs baseline: 1.1867x; 1.1867x over previous
//
#include <hip/hip_runtime.h>

#define M_ROWS 1024
#define DIM 512
#define NB 1024              // row bytes = DIM*2
#define N_TOT 7168           // M + 2*M*C
#define TEXT_OFF 1024
#define SHUF_OFF 4096
#define INV_T (1.0f/0.07f)
#define MARGIN_V 0.2f
#define TILES 56             // N_TOT / 128

typedef __attribute__((ext_vector_type(8))) short bf16x8;
typedef __attribute__((ext_vector_type(4))) float f32x4;

typedef const __attribute__((address_space(1))) unsigned int gas_uint;
typedef __attribute__((address_space(3))) unsigned int las_uint;

__device__ __forceinline__ void gload16(const void* g, void* l) {
  __builtin_amdgcn_global_load_lds((gas_uint*)g, (las_uint*)l, 16, 0, 0);
}

__device__ __forceinline__ ushort f2bf(float f) {
  unsigned u = __float_as_uint(f);
  u += 0x7fffu + ((u >> 16) & 1u);   // RTNE
  return (ushort)(u >> 16);
}

// ---------------- Kernel 1: normalize + cast bf16 + build ids ----------------
__global__ __launch_bounds__(256) void k_normalize(
    const float* __restrict__ motion, const float* __restrict__ text,
    const float* __restrict__ shuf, const int* __restrict__ mids,
    ushort* __restrict__ emb, int* __restrict__ ids) {
  int wave = threadIdx.x >> 6;
  int lane = threadIdx.x & 63;
  int row = blockIdx.x * 4 + wave;
  if (row >= N_TOT) return;
  const float* src;
  int id;
  if (row < TEXT_OFF) { src = motion + (size_t)row * DIM; id = mids[row]; }
  else if (row < SHUF_OFF) { int r = row - TEXT_OFF; src = text + (size_t)r * DIM; id = mids[r / 3]; }
  else { int r = row - SHUF_OFF; src = shuf + (size_t)r * DIM; id = mids[r / 3] + 100000; }

  float4 a = ((const float4*)src)[lane * 2];
  float4 b = ((const float4*)src)[lane * 2 + 1];
  float v0 = a.x + 1e-8f, v1 = a.y + 1e-8f, v2 = a.z + 1e-8f, v3 = a.w + 1e-8f;
  float v4 = b.x + 1e-8f, v5 = b.y + 1e-8f, v6 = b.z + 1e-8f, v7 = b.w + 1e-8f;
  float ss = v0*v0 + v1*v1 + v2*v2 + v3*v3 + v4*v4 + v5*v5 + v6*v6 + v7*v7;
  #pragma unroll
  for (int m = 1; m < 64; m <<= 1) ss += __shfl_xor(ss, m);
  float inv = 1.0f / fmaxf(sqrtf(ss), 1e-12f);

  uint w0 = (uint)f2bf(v0 * inv) | ((uint)f2bf(v1 * inv) << 16);
  uint w1 = (uint)f2bf(v2 * inv) | ((uint)f2bf(v3 * inv) << 16);
  uint w2 = (uint)f2bf(v4 * inv) | ((uint)f2bf(v5 * inv) << 16);
  uint w3 = (uint)f2bf(v6 * inv) | ((uint)f2bf(v7 * inv) << 16);
  uint4 pk; pk.x = w0; pk.y = w1; pk.z = w2; pk.w = w3;
  *((uint4*)(emb + (size_t)row * DIM + lane * 8)) = pk;
  if (lane == 0) ids[row] = id;
}

// -------- Kernel 2: symmetric fused A*A^T + masked row/col reductions --------
// Only upper-triangular 128x128 tiles (x<=y). Off-diagonal tiles accumulate
// both row-side (i) and column-side (j) partials, exploiting sim symmetry.
__global__ __launch_bounds__(256) void k_gemm_loss(
    const ushort* __restrict__ emb, const int* __restrict__ ids,
    float* __restrict__ denom, float* __restrict__ possum, float* __restrict__ margsum) {
  __shared__ ushort As[128 * 32];   // linear [row][32] bf16, 8 KB
  __shared__ ushort Bs[128 * 32];
  __shared__ int rid[128];
  __shared__ int cid[128];

  // triangular tile decode: bid -> (x, y), x <= y
  int bid = blockIdx.x;
  int x = 0;
  while (bid >= TILES - x) { bid -= TILES - x; x++; }
  int y = x + bid;
  bool diag = (x == y);
  int brow = x * 128, bcol = y * 128;

  int t = threadIdx.x;
  int lane = t & 63;
  int wave = t >> 6;

  if (t < 128) rid[t] = ids[brow + t];
  else cid[t - 128] = ids[bcol + (t - 128)];

  // staging geometry: per K-step the 128x32 tile (8 KB) is written by
  // 2 gload calls per wave; call c covers LDS bytes [c*4096 + wave*1024, +1024)
  int srow0 = wave * 16 + (lane >> 2);        // rows 0..63   (c=0)
  int srow1 = 64 + wave * 16 + (lane >> 2);   // rows 64..127 (c=1)
  int scolb = (lane & 3) * 16;                // byte offset within 64B row
  const char* gA = (const char*)emb + (size_t)brow * NB;
  const char* gB = (const char*)emb + (size_t)bcol * NB;
  ushort* ldsA0 = As + wave * 512;            // byte base wave*1024
  ushort* ldsA1 = As + 2048 + wave * 512;     // byte base 4096 + wave*1024
  ushort* ldsB0 = Bs + wave * 512;
  ushort* ldsB1 = Bs + 2048 + wave * 512;

  int wrow = (wave >> 1) * 64;
  int wcol = (wave & 1) * 64;
  int fr = lane & 15;                 // fragment row-within-16
  int fc = (lane >> 4) * 8;           // fragment K offset (ushort elems)

  f32x4 acc[4][4];
  #pragma unroll
  for (int m = 0; m < 4; m++)
    #pragma unroll
    for (int n = 0; n < 4; n++)
      acc[m][n] = (f32x4){0.f, 0.f, 0.f, 0.f};

  for (int kk = 0; kk < DIM; kk += 32) {
    int kb = kk * 2;
    gload16(gA + (size_t)srow0 * NB + kb + scolb, ldsA0);
    gload16(gA + (size_t)srow1 * NB + kb + scolb, ldsA1);
    gload16(gB + (size_t)srow0 * NB + kb + scolb, ldsB0);
    gload16(gB + (size_t)srow1 * NB + kb + scolb, ldsB1);
    __syncthreads();   // drains vmcnt: staged data visible to all waves

    bf16x8 aF[4], bF[4];
    #pragma unroll
    for (int m = 0; m < 4; m++)
      aF[m] = *(const bf16x8*)(As + (size_t)(wrow + m * 16 + fr) * 32 + fc);
    #pragma unroll
    for (int n = 0; n < 4; n++)
      bF[n] = *(const bf16x8*)(Bs + (size_t)(wcol + n * 16 + fr) * 32 + fc);
    #pragma unroll
    for (int m = 0; m < 4; m++)
      #pragma unroll
      for (int n = 0; n < 4; n++)
        acc[m][n] = __builtin_amdgcn_mfma_f32_16x16x32_bf16(aF[m], bF[n], acc[m][n], 0, 0, 0);
    __syncthreads();   // before next K-step overwrites LDS
  }

  // Epilogue: per-element masks + row partials (i) and column partials (j).
  int cgrp = lane >> 4;   // 0..3
  int cl = lane & 15;
  float cd[4], cp[4], cm[4];
  #pragma unroll
  for (int n = 0; n < 4; n++) { cd[n] = 0.f; cp[n] = 0.f; cm[n] = 0.f; }

  #pragma unroll
  for (int m = 0; m < 4; m++) {
    #pragma unroll
    for (int r = 0; r < 4; r++) {
      int row_l = wrow + m * 16 + cgrp * 4 + r;
      int i = brow + row_l;
      int idi = rid[row_l];
      float dsum = 0.f, psum = 0.f, msum = 0.f;
      #pragma unroll
      for (int n = 0; n < 4; n++) {
        int col_l = wcol + n * 16 + cl;
        int j = bcol + col_l;
        float sim = acc[m][n][r] * INV_T;
        bool live = (!diag) || (i != j);
        if (live) {
          float e = __expf(sim);
          float hinge = fmaxf(sim + MARGIN_V, 0.f);
          bool same = (idi == cid[col_l]);
          float ps = same ? sim : 0.f;
          float ms = same ? 0.f : hinge;
          dsum += e; psum += ps; msum += ms;
          if (!diag) { cd[n] += e; cp[n] += ps; cm[n] += ms; }
        }
      }
      #pragma unroll
      for (int s = 1; s < 16; s <<= 1) {
        dsum += __shfl_xor(dsum, s);
        psum += __shfl_xor(psum, s);
        msum += __shfl_xor(msum, s);
      }
      if (cl == 0) {
        atomicAdd(&denom[i], dsum);
        atomicAdd(&possum[i], psum);
        atomicAdd(&margsum[i], msum);
      }
    }
  }

  if (!diag) {
    #pragma unroll
    for (int n = 0; n < 4; n++) {
      float d = cd[n], p = cp[n], mm = cm[n];
      d += __shfl_xor(d, 16); d += __shfl_xor(d, 32);
      p += __shfl_xor(p, 16); p += __shfl_xor(p, 32);
      mm += __shfl_xor(mm, 16); mm += __shfl_xor(mm, 32);
      if (lane < 16) {
        int j = bcol + wcol + n * 16 + cl;
        atomicAdd(&denom[j], d);
        atomicAdd(&possum[j], p);
        atomicAdd(&margsum[j], mm);
      }
    }
  }
}

// ---------------- Kernel 3: finalize ----------------
__global__ __launch_bounds__(256) void k_finalize(
    const int* __restrict__ mids, const float* __restrict__ denom,
    const float* __restrict__ possum, const float* __restrict__ margsum,
    float* __restrict__ out) {
  __shared__ int hist[256];
  __shared__ double red[256];
  __shared__ int redc[256];
  int t = threadIdx.x;
  hist[t] = 0;
  __syncthreads();
  for (int i = t; i < M_ROWS; i += 256) atomicAdd(&hist[mids[i]], 1);
  __syncthreads();

  double tot = 0.0;
  int cnt = 0;
  for (int i = t; i < N_TOT; i += 256) {
    int v; bool shuf = false;
    if (i < TEXT_OFF) v = mids[i];
    else if (i < SHUF_OFF) v = mids[(i - TEXT_OFF) / 3];
    else { v = mids[(i - SHUF_OFF) / 3]; shuf = true; }
    int c = hist[v];
    int npos = shuf ? (3 * c - 1) : (4 * c - 1);
    int nneg = N_TOT - 1 - npos;
    if (npos > 0 && nneg > 0) {
      float infonce = logf(denom[i]) - possum[i] / (float)(npos > 1 ? npos : 1);
      float marg = margsum[i] / (float)(nneg > 1 ? nneg : 1);
      tot += (double)(infonce + marg);
      cnt++;
    }
  }
  red[t] = tot; redc[t] = cnt;
  __syncthreads();
  for (int s = 128; s > 0; s >>= 1) {
    if (t < s) { red[t] += red[t + s]; redc[t] += redc[t + s]; }
    __syncthreads();
  }
  if (t == 0) {
    out[0] = (redc[0] > 0) ? (float)(red[0] / (double)redc[0]) : 0.f;
  }
}

// ---------------- Launch ----------------
extern "C" void kernel_launch(void* const* d_in, const int* in_sizes, int n_in,
                              void* d_out, int out_size, void* d_ws, size_t ws_size,
                              hipStream_t stream) {
  const float* motion = (const float*)d_in[0];
  const float* text   = (const float*)d_in[1];
  const float* shuf   = (const float*)d_in[2];
  const int*   mids   = (const int*)d_in[3];

  char* ws = (char*)d_ws;
  ushort* emb = (ushort*)ws;                                  // N*D bf16 = 7,340,032 B
  int* ids    = (int*)(ws + (size_t)N_TOT * DIM * 2);         // N*4
  float* denom = (float*)(ws + (size_t)N_TOT * DIM * 2 + (size_t)N_TOT * 4);
  float* possum  = denom + N_TOT;
  float* margsum = denom + 2 * N_TOT;

  hipMemsetAsync(denom, 0, 3 * (size_t)N_TOT * sizeof(float), stream);

  k_normalize<<<N_TOT / 4, 256, 0, stream>>>(motion, text, shuf, mids, emb, ids);
  int nblk = TILES * (TILES + 1) / 2;   // 1596 upper-triangular tiles
  k_gemm_loss<<<nblk, 256, 0, stream>>>(emb, ids, denom, possum, margsum);
  k_finalize<<<1, 256, 0, stream>>>(mids, denom, possum, margsum, (float*)d_out);
}